// Round 11
// baseline (586.641 us; speedup 1.0000x reference)
//
#include <hip/hip_runtime.h>
#include <stdint.h>

// NCA: B=8, C=16, H=W=128, hidden=128, 8 steps.
// ws: [0,8MB) midA, [8MB,16MB) midB, [16MB,+25.2MB) p4 (perceived, quad-
// interleaved fp32), [+128KB) pre, [+128KB) fb, [+2MB) mask, [+32KB) w. ~44MB.

#define BATCH 8
#define CH 16
#define HT 128
#define WD 128
#define HIDN 128
#define PLANE (HT*WD)
#define IMG (CH*PLANE)
#define NELEM (BATCH*IMG)
#define NPIX (BATCH*PLANE)
#define WORDS_PER_STEP (NELEM/32)
#define NSTEPS 8
#define RROW 65      // red row stride: odd -> conflict-free

struct Keys { unsigned k[2*NSTEPS]; };

__host__ __device__ __forceinline__ unsigned rotl32u(unsigned v, int r) {
  return (v << r) | (v >> (32 - r));
}

// JAX threefry2x32 (20 rounds).
__host__ __device__ __forceinline__ void tf2x32(unsigned k0, unsigned k1,
                                                unsigned c0, unsigned c1,
                                                unsigned &o0, unsigned &o1) {
  const unsigned ks2 = k0 ^ k1 ^ 0x1BD11BDAu;
  unsigned x0 = c0 + k0, x1 = c1 + k1;
  x0 += x1; x1 = rotl32u(x1, 13); x1 ^= x0;
  x0 += x1; x1 = rotl32u(x1, 15); x1 ^= x0;
  x0 += x1; x1 = rotl32u(x1, 26); x1 ^= x0;
  x0 += x1; x1 = rotl32u(x1,  6); x1 ^= x0;
  x0 += k1; x1 += ks2 + 1u;
  x0 += x1; x1 = rotl32u(x1, 17); x1 ^= x0;
  x0 += x1; x1 = rotl32u(x1, 29); x1 ^= x0;
  x0 += x1; x1 = rotl32u(x1, 16); x1 ^= x0;
  x0 += x1; x1 = rotl32u(x1, 24); x1 ^= x0;
  x0 += ks2; x1 += k0 + 2u;
  x0 += x1; x1 = rotl32u(x1, 13); x1 ^= x0;
  x0 += x1; x1 = rotl32u(x1, 15); x1 ^= x0;
  x0 += x1; x1 = rotl32u(x1, 26); x1 ^= x0;
  x0 += x1; x1 = rotl32u(x1,  6); x1 ^= x0;
  x0 += k0; x1 += k1 + 3u;
  x0 += x1; x1 = rotl32u(x1, 17); x1 ^= x0;
  x0 += x1; x1 = rotl32u(x1, 29); x1 ^= x0;
  x0 += x1; x1 = rotl32u(x1, 16); x1 ^= x0;
  x0 += x1; x1 = rotl32u(x1, 24); x1 ^= x0;
  x0 += k1; x1 += ks2 + 4u;
  x0 += x1; x1 = rotl32u(x1, 13); x1 ^= x0;
  x0 += x1; x1 = rotl32u(x1, 15); x1 ^= x0;
  x0 += x1; x1 = rotl32u(x1, 26); x1 ^= x0;
  x0 += x1; x1 = rotl32u(x1,  6); x1 ^= x0;
  x0 += ks2; x1 += k0 + 5u;
  o0 = x0; o1 = x1;
}

// Precomputed dropout masks (r8-validated; inline-per-step was a 12us/step
// codegen loss in r10).
__global__ __launch_bounds__(256) void mask_kernel(unsigned* __restrict__ mask,
                                                   Keys keys) {
  unsigned t = blockIdx.x * 256u + threadIdx.x;
  unsigned step = t >> 16;
  unsigned k0 = keys.k[2*step], k1 = keys.k[2*step + 1];
  unsigned base = (t & 65535u) << 5;
  unsigned word = 0u;
  #pragma unroll 4
  for (int i = 0; i < 32; ++i) {
    unsigned b1x, b2x;
    tf2x32(k0, k1, 0u, base + (unsigned)i, b1x, b2x);
    unsigned bits = b1x ^ b2x;
    word |= (((bits >> 9) != 0u) ? 1u : 0u) << i;
  }
  mask[t] = word;
}

// w1T[c][h] = w1[h][c]; w2T[h][o] = w2[o][h].
__global__ __launch_bounds__(256) void wpack_kernel(
    const float* __restrict__ w1, const float* __restrict__ w2,
    float* __restrict__ w1T, float* __restrict__ w2T) {
  int t = blockIdx.x * 256 + threadIdx.x;   // 8192
  if (t < 48 * HIDN) {
    int c = t >> 7, h = t & 127;
    w1T[t] = w1[h * 48 + c];
  } else {
    int i = t - 48 * HIDN;
    int h = i >> 4, o = i & 15;
    w2T[i] = w2[o * HIDN + h];
  }
}

// fmask: f(s) = pre(s) & (maxpool3(mid3(s)) > 0.1), one byte per pixel.
__global__ __launch_bounds__(256) void fmask_kernel(
    const float* __restrict__ mid,
    const unsigned char* __restrict__ pre,
    unsigned char* __restrict__ fb) {
  int t = blockIdx.x * 256 + threadIdx.x;   // NPIX
  int b = t >> 14;
  int r = t & 16383;
  int y = r >> 7, x = r & 127;
  const float* m3 = mid + b * IMG + 3 * PLANE;
  float mx = -1e30f;
  #pragma unroll
  for (int dy = -1; dy <= 1; ++dy) {
    int yy = y + dy; if ((unsigned)yy >= HT) continue;
    #pragma unroll
    for (int dxx = -1; dxx <= 1; ++dxx) {
      int xx = x + dxx;
      if ((unsigned)xx < WD) mx = fmaxf(mx, m3[yy * WD + xx]);
    }
  }
  fb[t] = ((mx > 0.1f) && pre[t]) ? 1 : 0;
}

// Perceive kernel: one thread per pixel. Computes p[48] (id/sobelx/sobely,
// taps x f) and stores quad-interleaved: p4[q][pid] = {p[4q..4q+3]}, fp32.
// Channel-quad k writes p-quads {k, 4+k, 8+k} as b128 stores. Also writes
// pre byte (premax of masked ch-3 taps, r10-validated semantics).
template <int FUSED>
__global__ __launch_bounds__(256) void perceive_kernel(
    const float* __restrict__ src,
    const unsigned char* __restrict__ fprev,
    float4* __restrict__ p4,          // [12][NPIX]
    unsigned char* __restrict__ pre_out) {
  const int pid = blockIdx.x * 256 + threadIdx.x;
  const int b = pid >> 14, r = pid & 16383;
  const int y = r >> 7, x = r & 127;
  const bool yu = (y > 0), yd = (y < HT - 1), xl = (x > 0), xr = (x < WD - 1);

  float f00 = 1.f, f01 = 1.f, f02 = 1.f, f10 = 1.f, f11 = 1.f,
        f12 = 1.f, f20 = 1.f, f21 = 1.f, f22 = 1.f;
  if (FUSED) {
    const unsigned char* fp = fprev + b * PLANE + y * WD + x;
    f11 = (float)fp[0];
    f00 = (yu && xl) ? (float)fp[-WD - 1] : 0.f;
    f01 = yu         ? (float)fp[-WD]     : 0.f;
    f02 = (yu && xr) ? (float)fp[-WD + 1] : 0.f;
    f10 = xl         ? (float)fp[-1]      : 0.f;
    f12 = xr         ? (float)fp[1]       : 0.f;
    f20 = (yd && xl) ? (float)fp[WD - 1]  : 0.f;
    f21 = yd         ? (float)fp[WD]      : 0.f;
    f22 = (yd && xr) ? (float)fp[WD + 1]  : 0.f;
  }

  const float* sb = src + b * IMG + y * WD + x;
  float premax = -1e30f;
  #pragma unroll
  for (int k = 0; k < 4; ++k) {        // channel quads
    float id[4], sx[4], sy[4];
    #pragma unroll
    for (int cc = 0; cc < 4; ++cc) {
      const int ch = 4 * k + cc;
      const float* sc = sb + ch * PLANE;
      float a11 = sc[0] * f11;
      float a00 = (yu && xl) ? sc[-WD - 1] * f00 : 0.f;
      float a01 = yu         ? sc[-WD]     * f01 : 0.f;
      float a02 = (yu && xr) ? sc[-WD + 1] * f02 : 0.f;
      float a10 = xl         ? sc[-1]      * f10 : 0.f;
      float a12 = xr         ? sc[1]       * f12 : 0.f;
      float a20 = (yd && xl) ? sc[WD - 1]  * f20 : 0.f;
      float a21 = yd         ? sc[WD]      * f21 : 0.f;
      float a22 = (yd && xr) ? sc[WD + 1]  * f22 : 0.f;
      id[cc] = a11;
      sx[cc] = (a02 - a00) + 2.f * (a12 - a10) + (a22 - a20);
      sy[cc] = (a20 - a00) + 2.f * (a21 - a01) + (a22 - a02);
      if (ch == 3) {
        float m0 = fmaxf(fmaxf(a00, a01), fmaxf(a02, a10));
        float m1 = fmaxf(fmaxf(a11, a12), fmaxf(a20, a21));
        premax = fmaxf(fmaxf(m0, m1), a22);
      }
    }
    p4[(k)     * NPIX + pid] = make_float4(id[0], id[1], id[2], id[3]);
    p4[(4 + k) * NPIX + pid] = make_float4(sx[0], sx[1], sx[2], sx[3]);
    p4[(8 + k) * NPIX + pid] = make_float4(sy[0], sy[1], sy[2], sy[3]);
  }
  pre_out[pid] = (premax > 0.1f) ? 1 : 0;
}

// MLP kernel. 512 threads = 64 pixels x 8 hid-groups (wave-uniform g via
// readfirstlane). p comes from GLOBAL (vmcnt) while weights come from the
// scalar cache (lgkmcnt) — independent counters, so consuming p does NOT
// drain the s_load prefetch queue (the r5-r10 stall: ds_read+s_load shared
// lgkm, SMEM is OOO => every p read forced lgkmcnt(0)). Barrier-free until
// the final dx reduction.
__global__ __launch_bounds__(512) void mlp_kernel(
    const float4* __restrict__ p4,    // [12][NPIX]
    const float* __restrict__ w1T,    // [48][128]
    const float* __restrict__ w2T,    // [128][16]
    const float* __restrict__ bias1,  // [128]
    const float* __restrict__ bias2,  // [16]
    const unsigned* __restrict__ mask,
    float* __restrict__ mid) {
  __shared__ float red[64 * RROW];    // 16.6 KB

  const int tid = threadIdx.x;
  const int pix = tid & 63;
  const int g = __builtin_amdgcn_readfirstlane(tid >> 6);  // wave-uniform 0..7
  const int pid0 = blockIdx.x * 64;
  const int pid = pid0 + pix;
  const int b = pid0 >> 14;
  const int r0 = pid0 & 16383;
  const int y = r0 >> 7, x0 = r0 & 127;

  float t16[16];
  {
    const float* b1c = bias1 + g * 16;
    #pragma unroll
    for (int j = 0; j < 16; ++j) t16[j] = b1c[j];
  }
  #pragma unroll 4
  for (int q = 0; q < 12; ++q) {
    const float4 pq = p4[q * NPIX + pid];             // global b128, vmcnt
    const float* wr0 = w1T + (4 * q) * HIDN + g * 16; // s_load_x16, lgkm
    const float* wr1 = wr0 + HIDN;
    const float* wr2 = wr1 + HIDN;
    const float* wr3 = wr2 + HIDN;
    #pragma unroll
    for (int j = 0; j < 16; ++j) {
      float tj = t16[j];
      tj = fmaf(pq.x, wr0[j], tj);
      tj = fmaf(pq.y, wr1[j], tj);
      tj = fmaf(pq.z, wr2[j], tj);
      tj = fmaf(pq.w, wr3[j], tj);
      t16[j] = tj;
    }
  }
  float dx[16];
  #pragma unroll
  for (int o = 0; o < 16; ++o) dx[o] = 0.f;
  #pragma unroll 4
  for (int j = 0; j < 16; ++j) {
    float h = fmaxf(t16[j], 0.f);
    const float* w2r = w2T + (g * 16 + j) * 16;       // s_load_x16
    #pragma unroll
    for (int o = 0; o < 16; ++o) dx[o] = fmaf(h, w2r[o], dx[o]);
  }

  // two-stage dx reduction (only cross-wave point in the kernel)
  if (g < 4) {
    #pragma unroll
    for (int o = 0; o < 16; ++o) red[pix * RROW + g * 16 + o] = dx[o];
  }
  __syncthreads();
  if (g >= 4) {
    #pragma unroll
    for (int o = 0; o < 16; ++o) red[pix * RROW + (g - 4) * 16 + o] += dx[o];
  }
  __syncthreads();

  // epilogue: 1024 (pix,o) items over 512 threads
  const float* pf = (const float*)p4;
  #pragma unroll
  for (int k = 0; k < 2; ++k) {
    const int idx = tid + k * 512;
    const int p2 = idx & 63, o = idx >> 6;
    const int x2 = x0 + p2;
    const float* rr = red + p2 * RROW + o;
    float d = ((rr[0] + rr[16]) + (rr[32] + rr[48])) + bias2[o];
    d = fminf(fmaxf(d, -5.f), 5.f);
    unsigned mw = mask[((b * 16 + o) * HT + y) * 4 + (x2 >> 5)];
    float ident = pf[((size_t)(o >> 2) * NPIX + pid0 + p2) * 4 + (o & 3)];
    float v = ident + (((mw >> (x2 & 31)) & 1u) ? d : 0.f);
    mid[b * IMG + o * PLANE + r0 + p2] = v;
  }
}

// Final step_b: post-alive maxpool + apply pre&post, 4-way channel split.
__global__ __launch_bounds__(256) void step_b(
    const float* __restrict__ mid,
    const unsigned char* __restrict__ pre,
    float* __restrict__ out) {
  int t = blockIdx.x * 256 + threadIdx.x;   // NPIX threads
  int cq = t >> 15;
  int qid = t & 32767;
  int b = qid >> 12;
  int r = qid & 4095;
  int y = r >> 5;
  int x0 = (r & 31) * 4;
  const float* m3 = mid + b * IMG + 3 * PLANE;

  float col[6];
  #pragma unroll
  for (int j = 0; j < 6; ++j) {
    int xx = x0 - 1 + j;
    float m = -1e30f;
    if ((unsigned)xx < WD) {
      #pragma unroll
      for (int dy = -1; dy <= 1; ++dy) {
        int yy = y + dy;
        if ((unsigned)yy < HT) m = fmaxf(m, m3[yy * WD + xx]);
      }
    }
    col[j] = m;
  }

  const unsigned char* pr = pre + b * PLANE + y * WD + x0;
  float f[4];
  #pragma unroll
  for (int i = 0; i < 4; ++i) {
    float mx = fmaxf(fmaxf(col[i], col[i + 1]), col[i + 2]);
    f[i] = ((mx > 0.1f) && pr[i]) ? 1.f : 0.f;
  }

  #pragma unroll
  for (int cc = 0; cc < 4; ++cc) {
    int c = cq * 4 + cc;
    const float4 v = *(const float4*)&mid[b * IMG + c * PLANE + y * WD + x0];
    float4 w;
    w.x = v.x * f[0]; w.y = v.y * f[1]; w.z = v.z * f[2]; w.w = v.w * f[3];
    *(float4*)&out[b * IMG + c * PLANE + y * WD + x0] = w;
  }
}

extern "C" void kernel_launch(void* const* d_in, const int* in_sizes, int n_in,
                              void* d_out, int out_size, void* d_ws, size_t ws_size,
                              hipStream_t stream) {
  const float* x  = (const float*)d_in[0];
  const float* w1 = (const float*)d_in[1];
  const float* b1 = (const float*)d_in[2];
  const float* w2 = (const float*)d_in[3];
  const float* b2 = (const float*)d_in[4];
  float* out = (float*)d_out;

  char* ws = (char*)d_ws;
  float* midbuf[2];
  midbuf[0] = (float*)ws;
  midbuf[1] = (float*)(ws + (size_t)NELEM * 4);
  float4* p4 = (float4*)(ws + 2 * (size_t)NELEM * 4);
  char* after_p4 = ws + 2 * (size_t)NELEM * 4 + (size_t)12 * NPIX * 16;
  unsigned char* pre = (unsigned char*)after_p4;
  unsigned char* fb  = pre + NPIX;
  unsigned* mask = (unsigned*)(after_p4 + 2 * NPIX);
  float* w1T = (float*)(after_p4 + 2 * NPIX
                        + (size_t)NSTEPS * WORDS_PER_STEP * 4);
  float* w2T = w1T + 48 * HIDN;

  // keys = jax.random.split(key(42), 8): keys[j] = threefry2x32((0,42),(0,j))
  Keys keys;
  for (int j = 0; j < NSTEPS; ++j) {
    unsigned a, b;
    tf2x32(0u, 42u, 0u, (unsigned)j, a, b);
    keys.k[2 * j] = a; keys.k[2 * j + 1] = b;
  }

  mask_kernel<<<(NSTEPS * WORDS_PER_STEP) / 256, 256, 0, stream>>>(mask, keys);
  wpack_kernel<<<(48 * HIDN + HIDN * 16) / 256, 256, 0, stream>>>(w1, w2, w1T, w2T);

  for (int s = 0; s < NSTEPS; ++s) {
    if (s == 0) {
      perceive_kernel<0><<<NPIX / 256, 256, 0, stream>>>(
          x, (const unsigned char*)nullptr, p4, pre);
    } else {
      perceive_kernel<1><<<NPIX / 256, 256, 0, stream>>>(
          midbuf[(s - 1) & 1], fb, p4, pre);
    }
    mlp_kernel<<<NPIX / 64, 512, 0, stream>>>(
        p4, w1T, w2T, b1, b2, mask + s * WORDS_PER_STEP, midbuf[s & 1]);
    if (s < NSTEPS - 1)
      fmask_kernel<<<NPIX / 256, 256, 0, stream>>>(midbuf[s & 1], pre, fb);
  }
  step_b<<<NPIX / 256, 256, 0, stream>>>(
      midbuf[(NSTEPS - 1) & 1], pre, out);
}

// Round 12
// 365.894 us; speedup vs baseline: 1.6033x; 1.6033x over previous
//
#include <hip/hip_runtime.h>
#include <stdint.h>

// NCA: B=8, C=16, H=W=128, hidden=128, 8 steps.
// ws: [0,8MB) midA, [8MB,16MB) midB, [+512KB) mid3c, [+128KB) pre,
//     [+2MB) mask bits, [+24KB) w1T, [+8KB) w2T. ~18.7 MB.

#define BATCH 8
#define CH 16
#define HT 128
#define WD 128
#define HIDN 128
#define PLANE (HT*WD)
#define IMG (CH*PLANE)
#define NELEM (BATCH*IMG)
#define NPIX (BATCH*PLANE)
#define WORDS_PER_STEP (NELEM/32)
#define NSTEPS 8
#define NPIXB 64     // pixels per step_a block (half row)
#define RROW 65      // red row stride: odd -> conflict-free

struct Keys { unsigned k[2*NSTEPS]; };

__host__ __device__ __forceinline__ unsigned rotl32u(unsigned v, int r) {
  return (v << r) | (v >> (32 - r));
}

// JAX threefry2x32 (20 rounds).
__host__ __device__ __forceinline__ void tf2x32(unsigned k0, unsigned k1,
                                                unsigned c0, unsigned c1,
                                                unsigned &o0, unsigned &o1) {
  const unsigned ks2 = k0 ^ k1 ^ 0x1BD11BDAu;
  unsigned x0 = c0 + k0, x1 = c1 + k1;
  x0 += x1; x1 = rotl32u(x1, 13); x1 ^= x0;
  x0 += x1; x1 = rotl32u(x1, 15); x1 ^= x0;
  x0 += x1; x1 = rotl32u(x1, 26); x1 ^= x0;
  x0 += x1; x1 = rotl32u(x1,  6); x1 ^= x0;
  x0 += k1; x1 += ks2 + 1u;
  x0 += x1; x1 = rotl32u(x1, 17); x1 ^= x0;
  x0 += x1; x1 = rotl32u(x1, 29); x1 ^= x0;
  x0 += x1; x1 = rotl32u(x1, 16); x1 ^= x0;
  x0 += x1; x1 = rotl32u(x1, 24); x1 ^= x0;
  x0 += ks2; x1 += k0 + 2u;
  x0 += x1; x1 = rotl32u(x1, 13); x1 ^= x0;
  x0 += x1; x1 = rotl32u(x1, 15); x1 ^= x0;
  x0 += x1; x1 = rotl32u(x1, 26); x1 ^= x0;
  x0 += x1; x1 = rotl32u(x1,  6); x1 ^= x0;
  x0 += k0; x1 += k1 + 3u;
  x0 += x1; x1 = rotl32u(x1, 17); x1 ^= x0;
  x0 += x1; x1 = rotl32u(x1, 29); x1 ^= x0;
  x0 += x1; x1 = rotl32u(x1, 16); x1 ^= x0;
  x0 += x1; x1 = rotl32u(x1, 24); x1 ^= x0;
  x0 += k1; x1 += ks2 + 4u;
  x0 += x1; x1 = rotl32u(x1, 13); x1 ^= x0;
  x0 += x1; x1 = rotl32u(x1, 15); x1 ^= x0;
  x0 += x1; x1 = rotl32u(x1, 26); x1 ^= x0;
  x0 += x1; x1 = rotl32u(x1,  6); x1 ^= x0;
  x0 += ks2; x1 += k0 + 5u;
  o0 = x0; o1 = x1;
}

__global__ __launch_bounds__(256) void mask_kernel(unsigned* __restrict__ mask,
                                                   Keys keys) {
  unsigned t = blockIdx.x * 256u + threadIdx.x;
  unsigned step = t >> 16;
  unsigned k0 = keys.k[2*step], k1 = keys.k[2*step + 1];
  unsigned base = (t & 65535u) << 5;
  unsigned word = 0u;
  #pragma unroll 4
  for (int i = 0; i < 32; ++i) {
    unsigned b1x, b2x;
    tf2x32(k0, k1, 0u, base + (unsigned)i, b1x, b2x);
    unsigned bits = b1x ^ b2x;
    word |= (((bits >> 9) != 0u) ? 1u : 0u) << i;
  }
  mask[t] = word;
}

// w1T[c][h] = w1[h][c]; w2T[h][o] = w2[o][h].
__global__ __launch_bounds__(256) void wpack_kernel(
    const float* __restrict__ w1, const float* __restrict__ w2,
    float* __restrict__ w1T, float* __restrict__ w2T) {
  int t = blockIdx.x * 256 + threadIdx.x;   // 8192
  if (t < 48 * HIDN) {
    int c = t >> 7, h = t & 127;
    w1T[t] = w1[h * 48 + c];
  } else {
    int i = t - 48 * HIDN;
    int h = i >> 4, o = i & 15;
    w2T[i] = w2[o * HIDN + h];
  }
}

// Step kernel A — r8's measured-best kernel, unchanged except one predicated
// store of the ch3 plane snapshot (mid3c) in the epilogue.
// 512 threads = 64 pixels x 8 hid-groups; g via readfirstlane (r7 lesson).
__global__ __launch_bounds__(512) void step_a(
    const float* __restrict__ s,
    const float* __restrict__ w1T,   // [48][128]
    const float* __restrict__ w2T,   // [128][16]
    const float* __restrict__ bias1, // [128]
    const float* __restrict__ bias2, // [16]
    const unsigned* __restrict__ mask,
    float* __restrict__ mid,
    float* __restrict__ mid3c,       // ch3 snapshot (for fmaskzero)
    unsigned char* __restrict__ pre) {
  __shared__ float plds[48][NPIXB];      // 12.3 KB, conflict-free columns
  __shared__ float red[NPIXB * RROW];    // 16.6 KB

  const int tid = threadIdx.x;
  const int pix = tid & 63;
  const int g = __builtin_amdgcn_readfirstlane(tid >> 6);  // wave-uniform 0..7
  const int pid = blockIdx.x * NPIXB + pix;
  const int b = pid >> 14;
  const int r = pid & 16383;
  const int y = r >> 7, x = r & 127;

  // ---- perceive: this wave's 2 channels into LDS ----
  const float* sb = s + b * IMG;
  const int ctr = y * WD + x;
  const bool yu = (y > 0), yd = (y < HT - 1), xl = (x > 0), xr = (x < WD - 1);
  float premax = -1e30f;
  #pragma unroll
  for (int cc = 0; cc < 2; ++cc) {
    const int c = 2 * g + cc;
    const float* sc = sb + c * PLANE + ctr;
    float a11 = sc[0];
    float a00 = (yu && xl) ? sc[-WD - 1] : 0.f;
    float a01 = yu         ? sc[-WD]     : 0.f;
    float a02 = (yu && xr) ? sc[-WD + 1] : 0.f;
    float a10 = xl         ? sc[-1]      : 0.f;
    float a12 = xr         ? sc[1]       : 0.f;
    float a20 = (yd && xl) ? sc[WD - 1]  : 0.f;
    float a21 = yd         ? sc[WD]      : 0.f;
    float a22 = (yd && xr) ? sc[WD + 1]  : 0.f;
    plds[c][pix]      = a11;
    plds[16 + c][pix] = (a02 - a00) + 2.f * (a12 - a10) + (a22 - a20);
    plds[32 + c][pix] = (a20 - a00) + 2.f * (a21 - a01) + (a22 - a02);
    if (g == 1 && cc == 1) {           // c == 3, the alive channel
      float m0 = fmaxf(fmaxf(a00, a01), fmaxf(a02, a10));
      float m1 = fmaxf(fmaxf(a11, a12), fmaxf(a20, a21));
      premax = fmaxf(fmaxf(m0, m1), a22);
    }
  }
  __syncthreads();

  // ---- MLP: this wave's 16-hid chunk ----
  float t16[16];
  {
    const float* b1c = bias1 + g * 16;
    #pragma unroll
    for (int j = 0; j < 16; ++j) t16[j] = b1c[j];
  }
  #pragma unroll 2
  for (int c = 0; c < 48; ++c) {
    const float pc = plds[c][pix];             // ds_read_b32, conflict-free
    const float* wr = w1T + c * HIDN + g * 16; // s_load_dwordx16
    #pragma unroll
    for (int j = 0; j < 16; ++j) t16[j] = fmaf(pc, wr[j], t16[j]);
  }
  float dx[16];
  #pragma unroll
  for (int o = 0; o < 16; ++o) dx[o] = 0.f;
  #pragma unroll
  for (int j = 0; j < 16; ++j) {
    float h = fmaxf(t16[j], 0.f);
    const float* w2r = w2T + (g * 16 + j) * 16;  // s_load_dwordx16
    #pragma unroll
    for (int o = 0; o < 16; ++o) dx[o] = fmaf(h, w2r[o], dx[o]);
  }

  // ---- two-stage dx reduction in LDS ----
  if (g < 4) {
    #pragma unroll
    for (int o = 0; o < 16; ++o) red[pix * RROW + g * 16 + o] = dx[o];
  }
  __syncthreads();
  if (g >= 4) {
    #pragma unroll
    for (int o = 0; o < 16; ++o) red[pix * RROW + (g - 4) * 16 + o] += dx[o];
  }
  if (g == 1) pre[pid] = (premax > 0.1f) ? 1 : 0;
  __syncthreads();

  // ---- epilogue: 1024 (pix,o) items over 512 threads ----
  #pragma unroll
  for (int k = 0; k < 2; ++k) {
    const int idx = tid + k * 512;
    const int p2 = idx & 63, o = idx >> 6;
    const int pid2 = blockIdx.x * NPIXB + p2;
    const int b2i = pid2 >> 14;
    const int r2 = pid2 & 16383;
    const int y2 = r2 >> 7, x2 = r2 & 127;
    const float* rr = red + p2 * RROW + o;
    float d = ((rr[0] + rr[16]) + (rr[32] + rr[48])) + bias2[o];
    d = fminf(fmaxf(d, -5.f), 5.f);
    unsigned mw = mask[((b2i * 16 + o) * HT + y2) * 4 + (x2 >> 5)];
    float v = plds[o][p2] + (((mw >> (x2 & 31)) & 1u) ? d : 0.f);
    mid[b2i * IMG + o * PLANE + r2] = v;
    if (o == 3) mid3c[pid2] = v;     // ch3 snapshot for fmaskzero
  }
}

// fmaskzero: post = maxpool3(mid3c) > 0.1 (snapshot — race-free vs the
// in-place zeroing below); f = pre & post; dead pixels get all 16 channels
// of mid zeroed IN PLACE, so the next step_a reads an already-masked state
// with r8's unmodified hot loop. Replaces step_b's 33 MB round-trip with
// 0.7 MB + rare scattered stores.
__global__ __launch_bounds__(256) void fmaskzero_kernel(
    const float* __restrict__ mid3c,
    const unsigned char* __restrict__ pre,
    float* __restrict__ mid) {
  int t = blockIdx.x * 256 + threadIdx.x;   // NPIX
  int b = t >> 14;
  int r = t & 16383;
  int y = r >> 7, x = r & 127;
  const float* m3 = mid3c + b * PLANE;
  float mx = -1e30f;
  #pragma unroll
  for (int dy = -1; dy <= 1; ++dy) {
    int yy = y + dy; if ((unsigned)yy >= HT) continue;
    #pragma unroll
    for (int dxx = -1; dxx <= 1; ++dxx) {
      int xx = x + dxx;
      if ((unsigned)xx < WD) mx = fmaxf(mx, m3[yy * WD + xx]);
    }
  }
  if (!((mx > 0.1f) && pre[t])) {
    float* mp = mid + b * IMG + r;
    #pragma unroll
    for (int c = 0; c < CH; ++c) mp[c * PLANE] = 0.f;
  }
}

// Final step_b: post-alive maxpool + apply pre&post, 4-way channel split.
__global__ __launch_bounds__(256) void step_b(
    const float* __restrict__ mid,
    const unsigned char* __restrict__ pre,
    float* __restrict__ out) {
  int t = blockIdx.x * 256 + threadIdx.x;   // NPIX threads
  int cq = t >> 15;
  int qid = t & 32767;
  int b = qid >> 12;
  int r = qid & 4095;
  int y = r >> 5;
  int x0 = (r & 31) * 4;
  const float* m3 = mid + b * IMG + 3 * PLANE;

  float col[6];
  #pragma unroll
  for (int j = 0; j < 6; ++j) {
    int xx = x0 - 1 + j;
    float m = -1e30f;
    if ((unsigned)xx < WD) {
      #pragma unroll
      for (int dy = -1; dy <= 1; ++dy) {
        int yy = y + dy;
        if ((unsigned)yy < HT) m = fmaxf(m, m3[yy * WD + xx]);
      }
    }
    col[j] = m;
  }

  const unsigned char* pr = pre + b * PLANE + y * WD + x0;
  float f[4];
  #pragma unroll
  for (int i = 0; i < 4; ++i) {
    float mx = fmaxf(fmaxf(col[i], col[i + 1]), col[i + 2]);
    f[i] = ((mx > 0.1f) && pr[i]) ? 1.f : 0.f;
  }

  #pragma unroll
  for (int cc = 0; cc < 4; ++cc) {
    int c = cq * 4 + cc;
    const float4 v = *(const float4*)&mid[b * IMG + c * PLANE + y * WD + x0];
    float4 w;
    w.x = v.x * f[0]; w.y = v.y * f[1]; w.z = v.z * f[2]; w.w = v.w * f[3];
    *(float4*)&out[b * IMG + c * PLANE + y * WD + x0] = w;
  }
}

extern "C" void kernel_launch(void* const* d_in, const int* in_sizes, int n_in,
                              void* d_out, int out_size, void* d_ws, size_t ws_size,
                              hipStream_t stream) {
  const float* x  = (const float*)d_in[0];
  const float* w1 = (const float*)d_in[1];
  const float* b1 = (const float*)d_in[2];
  const float* w2 = (const float*)d_in[3];
  const float* b2 = (const float*)d_in[4];
  float* out = (float*)d_out;

  char* ws = (char*)d_ws;
  float* midbuf[2];
  midbuf[0] = (float*)ws;
  midbuf[1] = (float*)(ws + (size_t)NELEM * 4);
  float* mid3c = (float*)(ws + 2 * (size_t)NELEM * 4);
  unsigned char* pre = (unsigned char*)(ws + 2 * (size_t)NELEM * 4
                                           + (size_t)NPIX * 4);
  unsigned* mask = (unsigned*)(ws + 2 * (size_t)NELEM * 4
                                  + (size_t)NPIX * 4 + NPIX);
  float* w1T = (float*)(ws + 2 * (size_t)NELEM * 4 + (size_t)NPIX * 4 + NPIX
                           + (size_t)NSTEPS * WORDS_PER_STEP * 4);
  float* w2T = w1T + 48 * HIDN;

  // keys = jax.random.split(key(42), 8): keys[j] = threefry2x32((0,42),(0,j))
  Keys keys;
  for (int j = 0; j < NSTEPS; ++j) {
    unsigned a, b;
    tf2x32(0u, 42u, 0u, (unsigned)j, a, b);
    keys.k[2 * j] = a; keys.k[2 * j + 1] = b;
  }

  mask_kernel<<<(NSTEPS * WORDS_PER_STEP) / 256, 256, 0, stream>>>(mask, keys);
  wpack_kernel<<<(48 * HIDN + HIDN * 16) / 256, 256, 0, stream>>>(w1, w2, w1T, w2T);

  for (int s = 0; s < NSTEPS; ++s) {
    const float* src = (s == 0) ? x : midbuf[(s - 1) & 1];
    step_a<<<NPIX / NPIXB, 512, 0, stream>>>(
        src, w1T, w2T, b1, b2, mask + s * WORDS_PER_STEP,
        midbuf[s & 1], mid3c, pre);
    if (s < NSTEPS - 1)
      fmaskzero_kernel<<<NPIX / 256, 256, 0, stream>>>(
          mid3c, pre, midbuf[s & 1]);
  }
  step_b<<<NPIX / 256, 256, 0, stream>>>(
      midbuf[(NSTEPS - 1) & 1], pre, out);
}